// Round 15
// baseline (81.234 us; speedup 1.0000x reference)
//
#include <hip/hip_runtime.h>
#include <math.h>

#define BB 64
#define SS 2048
#define DD 512
#define NU 512
#define WIN 128
#define NSLICE 8
#define G_OFF   0
#define ST_OFF  64
#define EN_OFF  128
#define CNT_OFF 192
#define PART_OFF 1024   // float offset of partials inside d_ws

__device__ __forceinline__ float wave_reduce_sum(float v) {
    #pragma unroll
    for (int off = 32; off > 0; off >>= 1)
        v += __shfl_down(v, off, 64);
    return v;
}

__device__ __forceinline__ float wave_reduce_max(float v) {
    #pragma unroll
    for (int off = 32; off > 0; off >>= 1)
        v = fmaxf(v, __shfl_down(v, off, 64));
    return v;
}

__device__ __forceinline__ float dot4(const float4 a, const float4 b) {
    return a.x * b.x + a.y * b.y + a.z * b.z + a.w * b.w;
}

// Kernel 1.
// Blocks [0, 64): p-path (16-lane-group GEMV over Wq); also zeroes the
//   per-batch completion counter used by ctxA's folded reduction.
// Blocks [64, 64+4096): score, 32 rows/block (2 passes, 2-deep pipeline).
__global__ __launch_bounds__(256, 4) void score_p_kernel(const float* __restrict__ query,
                                                         const float* __restrict__ keys,
                                                         const int* __restrict__ key_lengths,
                                                         const float* __restrict__ Wq,
                                                         const float* __restrict__ wp,
                                                         float* __restrict__ score,
                                                         float* __restrict__ ws) {
    const int t    = threadIdx.x;
    const int wave = t >> 6;
    const int lane = t & 63;
    const int g    = lane >> 4;   // 4 rows per wave pass
    const int w    = lane & 15;   // 16 lanes span one 512-float row

    if (blockIdx.x < BB) {
        // ---- p path: one block per batch ----
        const int b = blockIdx.x;
        __shared__ float act[NU];
        __shared__ float wsum[4];

        if (t == 0) ((int*)ws)[CNT_OFF + b] = 0;   // reset ctx completion counter

        const float4* qv = (const float4*)(query + b * DD);
        const float4 q0 = qv[w],       q1 = qv[16 + w],  q2 = qv[32 + w],  q3 = qv[48 + w];
        const float4 q4 = qv[64 + w],  q5 = qv[80 + w],  q6 = qv[96 + w],  q7 = qv[112 + w];

        #pragma unroll 2
        for (int pass = 0; pass < 32; ++pass) {
            const int u = pass * 16 + wave * 4 + g;
            const float4* rv = (const float4*)(Wq + (size_t)u * DD);
            const float4 k0 = rv[w],       k1 = rv[16 + w],  k2 = rv[32 + w],  k3 = rv[48 + w];
            const float4 k4 = rv[64 + w],  k5 = rv[80 + w],  k6 = rv[96 + w],  k7 = rv[112 + w];
            const float s0 = dot4(k0, q0), s1 = dot4(k1, q1), s2 = dot4(k2, q2), s3 = dot4(k3, q3);
            const float s4 = dot4(k4, q4), s5 = dot4(k5, q5), s6 = dot4(k6, q6), s7 = dot4(k7, q7);
            float acc = ((s0 + s1) + (s2 + s3)) + ((s4 + s5) + (s6 + s7));
            #pragma unroll
            for (int m = 1; m < 16; m <<= 1)
                acc += __shfl_xor(acc, m, 64);
            if (w == 0) act[u] = tanhf(acc);
        }
        __syncthreads();

        float sv = act[t] * wp[t] + act[t + 256] * wp[t + 256];
        sv = wave_reduce_sum(sv);
        if (lane == 0) wsum[wave] = sv;
        __syncthreads();

        if (t == 0) {
            const float s = wsum[0] + wsum[1] + wsum[2] + wsum[3];
            const float sig = 1.0f / (1.0f + expf(-s));
            const float L = (float)key_lengths[b];
            const float p = L * sig;
            const int start = (int)(p - (float)WIN);   // trunc toward zero
            const int end   = (int)(p + (float)WIN);
            const float diff = L - p;
            const float gg = expf(-(diff * diff) / (float)WIN);
            ws[G_OFF + b] = gg;
            ((int*)ws)[ST_OFF + b] = start;
            ((int*)ws)[EN_OFF + b] = end;
        }
    } else {
        // ---- score path: software-pipelined 16-lane-group GEMV ----
        const int bid   = blockIdx.x - BB;
        const int b     = bid >> 6;   // 64 blocks per batch
        const int chunk = bid & 63;   // 32 rows per block
        const int r0    = chunk * 32 + wave * 8;

        const float4* qv = (const float4*)(query + b * DD);
        const float4 q0 = qv[w],       q1 = qv[16 + w],  q2 = qv[32 + w],  q3 = qv[48 + w];
        const float4 q4 = qv[64 + w],  q5 = qv[80 + w],  q6 = qv[96 + w],  q7 = qv[112 + w];

        const float4* kb = (const float4*)(keys + (size_t)b * SS * DD);

        // prologue: load pass 0
        const float4* rv = kb + (size_t)(r0 + g) * (DD / 4);
        float4 k0 = rv[w],       k1 = rv[16 + w],  k2 = rv[32 + w],  k3 = rv[48 + w];
        float4 k4 = rv[64 + w],  k5 = rv[80 + w],  k6 = rv[96 + w],  k7 = rv[112 + w];

        #pragma unroll
        for (int p = 0; p < 2; ++p) {
            float4 n0, n1, n2, n3, n4, n5, n6, n7;
            if (p < 1) {   // issue next pass's loads before this pass's reduce
                const float4* nv = kb + (size_t)(r0 + 4 + g) * (DD / 4);
                n0 = nv[w];       n1 = nv[16 + w];  n2 = nv[32 + w];  n3 = nv[48 + w];
                n4 = nv[64 + w];  n5 = nv[80 + w];  n6 = nv[96 + w];  n7 = nv[112 + w];
            }
            const float s0 = dot4(k0, q0), s1 = dot4(k1, q1), s2 = dot4(k2, q2), s3 = dot4(k3, q3);
            const float s4 = dot4(k4, q4), s5 = dot4(k5, q5), s6 = dot4(k6, q6), s7 = dot4(k7, q7);
            float acc = ((s0 + s1) + (s2 + s3)) + ((s4 + s5) + (s6 + s7));
            #pragma unroll
            for (int m = 1; m < 16; m <<= 1)
                acc += __shfl_xor(acc, m, 64);
            if (w == 0) score[b * SS + r0 + p * 4 + g] = acc;
            if (p < 1) {
                k0 = n0; k1 = n1; k2 = n2; k3 = n3;
                k4 = n4; k5 = n5; k6 = n6; k7 = n7;
            }
        }
    }
}

// Kernel 2: softmax stats + windowed weighted sum over a contiguous window
// SLICE, streamed linearly; LAST-ARRIVING block per batch also reduces the
// slice partials (decoupled completion via counter zeroed in kernel 1).
__global__ __launch_bounds__(256) void ctxA_kernel(const float* __restrict__ keys,
                                                   const float* __restrict__ score,
                                                   float* __restrict__ ws,
                                                   float* __restrict__ part,
                                                   float* __restrict__ ctx) {
    const int b     = blockIdx.x;
    const int slice = blockIdx.y;
    const int t     = threadIdx.x;
    const int wave  = t >> 6;
    const int lane  = t & 63;

    __shared__ float w_lds[40];
    __shared__ float redm[4], reds[4];
    __shared__ float4 part_l[128];
    __shared__ int is_last;

    const float* srow = score + b * SS;

    const float4 v0 = ((const float4*)srow)[t];
    const float4 v1 = ((const float4*)srow)[t + 256];
    float m = fmaxf(fmaxf(fmaxf(v0.x, v0.y), fmaxf(v0.z, v0.w)),
                    fmaxf(fmaxf(v1.x, v1.y), fmaxf(v1.z, v1.w)));
    m = wave_reduce_max(m);
    if (lane == 0) redm[wave] = m;
    __syncthreads();
    const float mx = fmaxf(fmaxf(redm[0], redm[1]), fmaxf(redm[2], redm[3]));

    float sum = expf(v0.x - mx) + expf(v0.y - mx) + expf(v0.z - mx) + expf(v0.w - mx)
              + expf(v1.x - mx) + expf(v1.y - mx) + expf(v1.z - mx) + expf(v1.w - mx);
    sum = wave_reduce_sum(sum);
    if (lane == 0) reds[wave] = sum;
    __syncthreads();
    const float inv = 1.0f / (reds[0] + reds[1] + reds[2] + reds[3]);

    const float gg   = ws[G_OFF + b];
    const int start  = ((const int*)ws)[ST_OFF + b];
    const int end    = ((const int*)ws)[EN_OFF + b];
    const int s_lo   = max(start, 0);
    const int s_hi   = min(end, SS);
    const int width  = s_hi - s_lo;              // in [0, 257]
    const int sliceN = (width + NSLICE - 1) / NSLICE;
    const int i_lo   = slice * sliceN;
    const int i_hi   = min(i_lo + sliceN, width);
    const int n      = i_hi - i_lo;              // may be <= 0

    for (int i = t; i < n; i += 256)
        w_lds[i] = expf(srow[s_lo + i_lo + i] - mx) * inv * gg;
    __syncthreads();

    const int myrow = t >> 7;        // 0 or 1
    const int c4    = t & 127;
    const float4* kb = (const float4*)(keys + ((size_t)b * SS + s_lo + i_lo) * DD);

    float4 acc = make_float4(0.f, 0.f, 0.f, 0.f);
    for (int i = myrow; i < n; i += 2) {
        const float4 k = kb[(size_t)i * (DD / 4) + c4];
        const float wg = w_lds[i];
        acc.x += wg * k.x; acc.y += wg * k.y; acc.z += wg * k.z; acc.w += wg * k.w;
    }

    if (myrow) part_l[c4] = acc;
    __syncthreads();
    if (!myrow) {
        const float4 o = part_l[c4];
        acc.x += o.x; acc.y += o.y; acc.z += o.z; acc.w += o.w;
        ((float4*)part)[((size_t)b * NSLICE + slice) * 128 + c4] = acc;
    }
    __syncthreads();

    if (t == 0) {
        __threadfence();                       // release our partial
        const int old = atomicAdd((int*)ws + CNT_OFF + b, 1);
        is_last = (old == NSLICE - 1);
    }
    __syncthreads();

    if (is_last) {
        __threadfence();                       // acquire all partials
        #pragma unroll
        for (int rep = 0; rep < 2; ++rep) {
            const int d = t + rep * 256;
            float s = 0.f;
            #pragma unroll
            for (int sl = 0; sl < NSLICE; ++sl)
                s += part[((size_t)b * NSLICE + sl) * DD + d];
            ctx[b * DD + d] = s;
        }
    }
}

extern "C" void kernel_launch(void* const* d_in, const int* in_sizes, int n_in,
                              void* d_out, int out_size, void* d_ws, size_t ws_size,
                              hipStream_t stream) {
    const float* query       = (const float*)d_in[0];
    const float* keys        = (const float*)d_in[1];
    const int*   key_lengths = (const int*)d_in[2];
    const float* Wq          = (const float*)d_in[3];
    const float* wp          = (const float*)d_in[4];

    float* ctx   = (float*)d_out;             // [64, 512]
    float* score = (float*)d_out + BB * DD;   // [64, 2048]
    float* ws    = (float*)d_ws;              // {g, start, end, cnt}
    float* part  = (float*)d_ws + PART_OFF;   // [64, NSLICE, 512]

    hipLaunchKernelGGL(score_p_kernel, dim3(BB + BB * 64), dim3(256), 0, stream,
                       query, keys, key_lengths, Wq, wp, score, ws);
    hipLaunchKernelGGL(ctxA_kernel, dim3(BB, NSLICE), dim3(256), 0, stream,
                       keys, score, ws, part, ctx);
}

// Round 16
// 79.686 us; speedup vs baseline: 1.0194x; 1.0194x over previous
//
#include <hip/hip_runtime.h>
#include <math.h>

#define BB 64
#define SS 2048
#define DD 512
#define NU 512
#define WIN 128
#define NSLICE 4
#define G_OFF   0
#define ST_OFF  64
#define EN_OFF  128
#define CNT_OFF 192
#define PART_OFF 1024   // float offset of partials inside d_ws

__device__ __forceinline__ float wave_reduce_sum(float v) {
    #pragma unroll
    for (int off = 32; off > 0; off >>= 1)
        v += __shfl_down(v, off, 64);
    return v;
}

__device__ __forceinline__ float wave_reduce_max(float v) {
    #pragma unroll
    for (int off = 32; off > 0; off >>= 1)
        v = fmaxf(v, __shfl_down(v, off, 64));
    return v;
}

__device__ __forceinline__ float dot4(const float4 a, const float4 b) {
    return a.x * b.x + a.y * b.y + a.z * b.z + a.w * b.w;
}

// Kernel 1.
// Blocks [0, 64): p-path (16-lane-group GEMV over Wq); zeroes the per-batch
//   completion counter for ctxA's folded reduction.
// Blocks [64, 64+2048): score, 64 rows/block, 4 passes, 2-deep pipeline
//   (identical to the R14 config that measured 67.4 us).
__global__ __launch_bounds__(256, 4) void score_p_kernel(const float* __restrict__ query,
                                                         const float* __restrict__ keys,
                                                         const int* __restrict__ key_lengths,
                                                         const float* __restrict__ Wq,
                                                         const float* __restrict__ wp,
                                                         float* __restrict__ score,
                                                         float* __restrict__ ws) {
    const int t    = threadIdx.x;
    const int wave = t >> 6;
    const int lane = t & 63;
    const int g    = lane >> 4;   // 4 rows per wave pass
    const int w    = lane & 15;   // 16 lanes span one 512-float row

    if (blockIdx.x < BB) {
        // ---- p path: one block per batch ----
        const int b = blockIdx.x;
        __shared__ float act[NU];
        __shared__ float wsum[4];

        if (t == 0) ((int*)ws)[CNT_OFF + b] = 0;   // reset ctx completion counter

        const float4* qv = (const float4*)(query + b * DD);
        const float4 q0 = qv[w],       q1 = qv[16 + w],  q2 = qv[32 + w],  q3 = qv[48 + w];
        const float4 q4 = qv[64 + w],  q5 = qv[80 + w],  q6 = qv[96 + w],  q7 = qv[112 + w];

        #pragma unroll 2
        for (int pass = 0; pass < 32; ++pass) {
            const int u = pass * 16 + wave * 4 + g;
            const float4* rv = (const float4*)(Wq + (size_t)u * DD);
            const float4 k0 = rv[w],       k1 = rv[16 + w],  k2 = rv[32 + w],  k3 = rv[48 + w];
            const float4 k4 = rv[64 + w],  k5 = rv[80 + w],  k6 = rv[96 + w],  k7 = rv[112 + w];
            const float s0 = dot4(k0, q0), s1 = dot4(k1, q1), s2 = dot4(k2, q2), s3 = dot4(k3, q3);
            const float s4 = dot4(k4, q4), s5 = dot4(k5, q5), s6 = dot4(k6, q6), s7 = dot4(k7, q7);
            float acc = ((s0 + s1) + (s2 + s3)) + ((s4 + s5) + (s6 + s7));
            #pragma unroll
            for (int m = 1; m < 16; m <<= 1)
                acc += __shfl_xor(acc, m, 64);
            if (w == 0) act[u] = tanhf(acc);
        }
        __syncthreads();

        float sv = act[t] * wp[t] + act[t + 256] * wp[t + 256];
        sv = wave_reduce_sum(sv);
        if (lane == 0) wsum[wave] = sv;
        __syncthreads();

        if (t == 0) {
            const float s = wsum[0] + wsum[1] + wsum[2] + wsum[3];
            const float sig = 1.0f / (1.0f + expf(-s));
            const float L = (float)key_lengths[b];
            const float p = L * sig;
            const int start = (int)(p - (float)WIN);   // trunc toward zero
            const int end   = (int)(p + (float)WIN);
            const float diff = L - p;
            const float gg = expf(-(diff * diff) / (float)WIN);
            ws[G_OFF + b] = gg;
            ((int*)ws)[ST_OFF + b] = start;
            ((int*)ws)[EN_OFF + b] = end;
        }
    } else {
        // ---- score path: software-pipelined 16-lane-group GEMV ----
        const int bid   = blockIdx.x - BB;
        const int b     = bid >> 5;   // 32 blocks per batch
        const int chunk = bid & 31;   // 64 rows per block
        const int r0    = chunk * 64 + wave * 16;

        const float4* qv = (const float4*)(query + b * DD);
        const float4 q0 = qv[w],       q1 = qv[16 + w],  q2 = qv[32 + w],  q3 = qv[48 + w];
        const float4 q4 = qv[64 + w],  q5 = qv[80 + w],  q6 = qv[96 + w],  q7 = qv[112 + w];

        const float4* kb = (const float4*)(keys + (size_t)b * SS * DD);

        // prologue: load pass 0
        const float4* rv = kb + (size_t)(r0 + g) * (DD / 4);
        float4 k0 = rv[w],       k1 = rv[16 + w],  k2 = rv[32 + w],  k3 = rv[48 + w];
        float4 k4 = rv[64 + w],  k5 = rv[80 + w],  k6 = rv[96 + w],  k7 = rv[112 + w];

        #pragma unroll
        for (int p = 0; p < 4; ++p) {
            float4 n0, n1, n2, n3, n4, n5, n6, n7;
            if (p < 3) {   // issue next pass's loads before this pass's reduce
                const float4* nv = kb + (size_t)(r0 + (p + 1) * 4 + g) * (DD / 4);
                n0 = nv[w];       n1 = nv[16 + w];  n2 = nv[32 + w];  n3 = nv[48 + w];
                n4 = nv[64 + w];  n5 = nv[80 + w];  n6 = nv[96 + w];  n7 = nv[112 + w];
            }
            const float s0 = dot4(k0, q0), s1 = dot4(k1, q1), s2 = dot4(k2, q2), s3 = dot4(k3, q3);
            const float s4 = dot4(k4, q4), s5 = dot4(k5, q5), s6 = dot4(k6, q6), s7 = dot4(k7, q7);
            float acc = ((s0 + s1) + (s2 + s3)) + ((s4 + s5) + (s6 + s7));
            #pragma unroll
            for (int m = 1; m < 16; m <<= 1)
                acc += __shfl_xor(acc, m, 64);
            if (w == 0) score[b * SS + r0 + p * 4 + g] = acc;
            if (p < 3) {
                k0 = n0; k1 = n1; k2 = n2; k3 = n3;
                k4 = n4; k5 = n5; k6 = n6; k7 = n7;
            }
        }
    }
}

// Kernel 2: softmax stats + windowed weighted sum over a contiguous window
// SLICE, streamed linearly; LAST-ARRIVING block per batch reduces the slice
// partials (decoupled completion via counter zeroed in kernel 1).
__global__ __launch_bounds__(256) void ctxA_kernel(const float* __restrict__ keys,
                                                   const float* __restrict__ score,
                                                   float* __restrict__ ws,
                                                   float* __restrict__ part,
                                                   float* __restrict__ ctx) {
    const int b     = blockIdx.x;
    const int slice = blockIdx.y;
    const int t     = threadIdx.x;
    const int wave  = t >> 6;
    const int lane  = t & 63;

    __shared__ float w_lds[72];
    __shared__ float redm[4], reds[4];
    __shared__ float4 part_l[128];
    __shared__ int is_last;

    const float* srow = score + b * SS;

    const float4 v0 = ((const float4*)srow)[t];
    const float4 v1 = ((const float4*)srow)[t + 256];
    float m = fmaxf(fmaxf(fmaxf(v0.x, v0.y), fmaxf(v0.z, v0.w)),
                    fmaxf(fmaxf(v1.x, v1.y), fmaxf(v1.z, v1.w)));
    m = wave_reduce_max(m);
    if (lane == 0) redm[wave] = m;
    __syncthreads();
    const float mx = fmaxf(fmaxf(redm[0], redm[1]), fmaxf(redm[2], redm[3]));

    float sum = expf(v0.x - mx) + expf(v0.y - mx) + expf(v0.z - mx) + expf(v0.w - mx)
              + expf(v1.x - mx) + expf(v1.y - mx) + expf(v1.z - mx) + expf(v1.w - mx);
    sum = wave_reduce_sum(sum);
    if (lane == 0) reds[wave] = sum;
    __syncthreads();
    const float inv = 1.0f / (reds[0] + reds[1] + reds[2] + reds[3]);

    const float gg   = ws[G_OFF + b];
    const int start  = ((const int*)ws)[ST_OFF + b];
    const int end    = ((const int*)ws)[EN_OFF + b];
    const int s_lo   = max(start, 0);
    const int s_hi   = min(end, SS);
    const int width  = s_hi - s_lo;              // in [0, 257]
    const int sliceN = (width + NSLICE - 1) / NSLICE;
    const int i_lo   = slice * sliceN;
    const int i_hi   = min(i_lo + sliceN, width);
    const int n      = i_hi - i_lo;              // may be <= 0

    for (int i = t; i < n; i += 256)
        w_lds[i] = expf(srow[s_lo + i_lo + i] - mx) * inv * gg;
    __syncthreads();

    const int myrow = t >> 7;        // 0 or 1
    const int c4    = t & 127;
    const float4* kb = (const float4*)(keys + ((size_t)b * SS + s_lo + i_lo) * DD);

    float4 acc = make_float4(0.f, 0.f, 0.f, 0.f);
    for (int i = myrow; i < n; i += 2) {
        const float4 k = kb[(size_t)i * (DD / 4) + c4];
        const float wg = w_lds[i];
        acc.x += wg * k.x; acc.y += wg * k.y; acc.z += wg * k.z; acc.w += wg * k.w;
    }

    if (myrow) part_l[c4] = acc;
    __syncthreads();
    if (!myrow) {
        const float4 o = part_l[c4];
        acc.x += o.x; acc.y += o.y; acc.z += o.z; acc.w += o.w;
        ((float4*)part)[((size_t)b * NSLICE + slice) * 128 + c4] = acc;
    }
    __syncthreads();

    if (t == 0) {
        __threadfence();                       // release our partial
        const int old = atomicAdd((int*)ws + CNT_OFF + b, 1);
        is_last = (old == NSLICE - 1);
    }
    __syncthreads();

    if (is_last) {
        __threadfence();                       // acquire all partials
        #pragma unroll
        for (int rep = 0; rep < 2; ++rep) {
            const int d = t + rep * 256;
            float s = 0.f;
            #pragma unroll
            for (int sl = 0; sl < NSLICE; ++sl)
                s += part[((size_t)b * NSLICE + sl) * DD + d];
            ctx[b * DD + d] = s;
        }
    }
}

extern "C" void kernel_launch(void* const* d_in, const int* in_sizes, int n_in,
                              void* d_out, int out_size, void* d_ws, size_t ws_size,
                              hipStream_t stream) {
    const float* query       = (const float*)d_in[0];
    const float* keys        = (const float*)d_in[1];
    const int*   key_lengths = (const int*)d_in[2];
    const float* Wq          = (const float*)d_in[3];
    const float* wp          = (const float*)d_in[4];

    float* ctx   = (float*)d_out;             // [64, 512]
    float* score = (float*)d_out + BB * DD;   // [64, 2048]
    float* ws    = (float*)d_ws;              // {g, start, end, cnt}
    float* part  = (float*)d_ws + PART_OFF;   // [64, NSLICE, 512]

    hipLaunchKernelGGL(score_p_kernel, dim3(BB + BB * 32), dim3(256), 0, stream,
                       query, keys, key_lengths, Wq, wp, score, ws);
    hipLaunchKernelGGL(ctxA_kernel, dim3(BB, NSLICE), dim3(256), 0, stream,
                       keys, score, ws, part, ctx);
}

// Round 17
// 63.702 us; speedup vs baseline: 1.2752x; 1.2509x over previous
//
#include <hip/hip_runtime.h>
#include <math.h>

#define BB 64
#define SS 2048
#define DD 512
#define NU 512
#define WIN 128
#define NSLICE 4
#define PART_OFF 1024   // float offset of partials inside d_ws

__device__ __forceinline__ float wave_reduce_sum(float v) {
    #pragma unroll
    for (int off = 32; off > 0; off >>= 1)
        v += __shfl_down(v, off, 64);
    return v;
}

__device__ __forceinline__ float wave_reduce_max(float v) {
    #pragma unroll
    for (int off = 32; off > 0; off >>= 1)
        v = fmaxf(v, __shfl_down(v, off, 64));
    return v;
}

__device__ __forceinline__ float dot4(const float4 a, const float4 b) {
    return a.x * b.x + a.y * b.y + a.z * b.z + a.w * b.w;
}

// Kernel 1 (identical to the R14 config that measured 67.4 us).
// Blocks [0, 64): p-path (16-lane-group GEMV over Wq).
// Blocks [64, 64+2048): score, 64 rows/block, 4 passes, 2-deep pipeline.
__global__ __launch_bounds__(256, 4) void score_p_kernel(const float* __restrict__ query,
                                                         const float* __restrict__ keys,
                                                         const int* __restrict__ key_lengths,
                                                         const float* __restrict__ Wq,
                                                         const float* __restrict__ wp,
                                                         float* __restrict__ score,
                                                         float* __restrict__ ws) {
    const int t    = threadIdx.x;
    const int wave = t >> 6;
    const int lane = t & 63;
    const int g    = lane >> 4;   // 4 rows per wave pass
    const int w    = lane & 15;   // 16 lanes span one 512-float row

    if (blockIdx.x < BB) {
        // ---- p path: one block per batch ----
        const int b = blockIdx.x;
        __shared__ float act[NU];
        __shared__ float wsum[4];

        const float4* qv = (const float4*)(query + b * DD);
        const float4 q0 = qv[w],       q1 = qv[16 + w],  q2 = qv[32 + w],  q3 = qv[48 + w];
        const float4 q4 = qv[64 + w],  q5 = qv[80 + w],  q6 = qv[96 + w],  q7 = qv[112 + w];

        #pragma unroll 2
        for (int pass = 0; pass < 32; ++pass) {
            const int u = pass * 16 + wave * 4 + g;
            const float4* rv = (const float4*)(Wq + (size_t)u * DD);
            const float4 k0 = rv[w],       k1 = rv[16 + w],  k2 = rv[32 + w],  k3 = rv[48 + w];
            const float4 k4 = rv[64 + w],  k5 = rv[80 + w],  k6 = rv[96 + w],  k7 = rv[112 + w];
            const float s0 = dot4(k0, q0), s1 = dot4(k1, q1), s2 = dot4(k2, q2), s3 = dot4(k3, q3);
            const float s4 = dot4(k4, q4), s5 = dot4(k5, q5), s6 = dot4(k6, q6), s7 = dot4(k7, q7);
            float acc = ((s0 + s1) + (s2 + s3)) + ((s4 + s5) + (s6 + s7));
            #pragma unroll
            for (int m = 1; m < 16; m <<= 1)
                acc += __shfl_xor(acc, m, 64);
            if (w == 0) act[u] = tanhf(acc);
        }
        __syncthreads();

        float sv = act[t] * wp[t] + act[t + 256] * wp[t + 256];
        sv = wave_reduce_sum(sv);
        if (lane == 0) wsum[wave] = sv;
        __syncthreads();

        if (t == 0) {
            const float s = wsum[0] + wsum[1] + wsum[2] + wsum[3];
            const float sig = 1.0f / (1.0f + expf(-s));
            const float L = (float)key_lengths[b];
            const float p = L * sig;
            const int start = (int)(p - (float)WIN);   // trunc toward zero
            const int end   = (int)(p + (float)WIN);
            const float diff = L - p;
            const float gg = expf(-(diff * diff) / (float)WIN);
            ws[b] = gg;
            ((int*)ws)[BB + b]     = start;
            ((int*)ws)[2 * BB + b] = end;
        }
    } else {
        // ---- score path: software-pipelined 16-lane-group GEMV ----
        const int bid   = blockIdx.x - BB;
        const int b     = bid >> 5;   // 32 blocks per batch
        const int chunk = bid & 31;   // 64 rows per block
        const int r0    = chunk * 64 + wave * 16;

        const float4* qv = (const float4*)(query + b * DD);
        const float4 q0 = qv[w],       q1 = qv[16 + w],  q2 = qv[32 + w],  q3 = qv[48 + w];
        const float4 q4 = qv[64 + w],  q5 = qv[80 + w],  q6 = qv[96 + w],  q7 = qv[112 + w];

        const float4* kb = (const float4*)(keys + (size_t)b * SS * DD);

        // prologue: load pass 0
        const float4* rv = kb + (size_t)(r0 + g) * (DD / 4);
        float4 k0 = rv[w],       k1 = rv[16 + w],  k2 = rv[32 + w],  k3 = rv[48 + w];
        float4 k4 = rv[64 + w],  k5 = rv[80 + w],  k6 = rv[96 + w],  k7 = rv[112 + w];

        #pragma unroll
        for (int p = 0; p < 4; ++p) {
            float4 n0, n1, n2, n3, n4, n5, n6, n7;
            if (p < 3) {   // issue next pass's loads before this pass's reduce
                const float4* nv = kb + (size_t)(r0 + (p + 1) * 4 + g) * (DD / 4);
                n0 = nv[w];       n1 = nv[16 + w];  n2 = nv[32 + w];  n3 = nv[48 + w];
                n4 = nv[64 + w];  n5 = nv[80 + w];  n6 = nv[96 + w];  n7 = nv[112 + w];
            }
            const float s0 = dot4(k0, q0), s1 = dot4(k1, q1), s2 = dot4(k2, q2), s3 = dot4(k3, q3);
            const float s4 = dot4(k4, q4), s5 = dot4(k5, q5), s6 = dot4(k6, q6), s7 = dot4(k7, q7);
            float acc = ((s0 + s1) + (s2 + s3)) + ((s4 + s5) + (s6 + s7));
            #pragma unroll
            for (int m = 1; m < 16; m <<= 1)
                acc += __shfl_xor(acc, m, 64);
            if (w == 0) score[b * SS + r0 + p * 4 + g] = acc;
            if (p < 3) {
                k0 = n0; k1 = n1; k2 = n2; k3 = n3;
                k4 = n4; k5 = n5; k6 = n6; k7 = n7;
            }
        }
    }
}

// Kernel 2 (stage A): softmax stats + windowed weighted sum over a contiguous
// window SLICE. 512 threads: stats phase reads one float4/thread; window loop
// keeps 4 rows in flight (myrow in 0..3) -> 2x the latency hiding of R14.
__global__ __launch_bounds__(512) void ctxA_kernel(const float* __restrict__ keys,
                                                   const float* __restrict__ score,
                                                   const float* __restrict__ ws,
                                                   float* __restrict__ part) {
    const int b     = blockIdx.x;
    const int slice = blockIdx.y;
    const int t     = threadIdx.x;
    const int wave  = t >> 6;
    const int lane  = t & 63;

    __shared__ float w_lds[72];
    __shared__ float redm[8], reds[8];
    __shared__ float4 part_l[3][128];

    const float* srow = score + b * SS;

    // softmax stats over S=2048: one float4 per thread
    const float4 v0 = ((const float4*)srow)[t];
    float m = fmaxf(fmaxf(v0.x, v0.y), fmaxf(v0.z, v0.w));
    m = wave_reduce_max(m);
    if (lane == 0) redm[wave] = m;
    __syncthreads();
    float mx = redm[0];
    #pragma unroll
    for (int i = 1; i < 8; ++i) mx = fmaxf(mx, redm[i]);

    float sum = expf(v0.x - mx) + expf(v0.y - mx) + expf(v0.z - mx) + expf(v0.w - mx);
    sum = wave_reduce_sum(sum);
    if (lane == 0) reds[wave] = sum;
    __syncthreads();
    float tot = 0.f;
    #pragma unroll
    for (int i = 0; i < 8; ++i) tot += reds[i];
    const float inv = 1.0f / tot;

    const float gg   = ws[b];
    const int start  = ((const int*)ws)[BB + b];
    const int end    = ((const int*)ws)[2 * BB + b];
    const int s_lo   = max(start, 0);
    const int s_hi   = min(end, SS);
    const int width  = s_hi - s_lo;              // in [0, 257]
    const int sliceN = (width + NSLICE - 1) / NSLICE;
    const int i_lo   = slice * sliceN;
    const int i_hi   = min(i_lo + sliceN, width);
    const int n      = i_hi - i_lo;              // may be <= 0

    for (int i = t; i < n; i += 512)
        w_lds[i] = expf(srow[s_lo + i_lo + i] - mx) * inv * gg;
    __syncthreads();

    // linear stream: 4 rows x 128 float4-cols per step, thread owns col group c4
    const int myrow = t >> 7;        // 0..3
    const int c4    = t & 127;
    const float4* kb = (const float4*)(keys + ((size_t)b * SS + s_lo + i_lo) * DD);

    float4 acc = make_float4(0.f, 0.f, 0.f, 0.f);
    for (int i = myrow; i < n; i += 4) {
        const float4 k = kb[(size_t)i * (DD / 4) + c4];
        const float wg = w_lds[i];
        acc.x += wg * k.x; acc.y += wg * k.y; acc.z += wg * k.z; acc.w += wg * k.w;
    }

    if (myrow) part_l[myrow - 1][c4] = acc;
    __syncthreads();
    if (myrow == 0) {
        #pragma unroll
        for (int r = 0; r < 3; ++r) {
            const float4 o = part_l[r][c4];
            acc.x += o.x; acc.y += o.y; acc.z += o.z; acc.w += o.w;
        }
        ((float4*)part)[((size_t)b * NSLICE + slice) * 128 + c4] = acc;
    }
}

// Kernel 2 (stage B): ctx[b][d] = sum over slices of partials
__global__ __launch_bounds__(512) void ctxB_kernel(const float* __restrict__ part,
                                                   float* __restrict__ ctx) {
    const int b = blockIdx.x;
    const int d = threadIdx.x;
    float s = 0.f;
    #pragma unroll
    for (int sl = 0; sl < NSLICE; ++sl)
        s += part[((size_t)b * NSLICE + sl) * DD + d];
    ctx[b * DD + d] = s;
}

extern "C" void kernel_launch(void* const* d_in, const int* in_sizes, int n_in,
                              void* d_out, int out_size, void* d_ws, size_t ws_size,
                              hipStream_t stream) {
    const float* query       = (const float*)d_in[0];
    const float* keys        = (const float*)d_in[1];
    const int*   key_lengths = (const int*)d_in[2];
    const float* Wq          = (const float*)d_in[3];
    const float* wp          = (const float*)d_in[4];

    float* ctx   = (float*)d_out;             // [64, 512]
    float* score = (float*)d_out + BB * DD;   // [64, 2048]
    float* ws    = (float*)d_ws;              // {g[64], start[64], end[64]}
    float* part  = (float*)d_ws + PART_OFF;   // [64, NSLICE, 512]

    hipLaunchKernelGGL(score_p_kernel, dim3(BB + BB * 32), dim3(256), 0, stream,
                       query, keys, key_lengths, Wq, wp, score, ws);
    hipLaunchKernelGGL(ctxA_kernel, dim3(BB, NSLICE), dim3(512), 0, stream,
                       keys, score, ws, part);
    hipLaunchKernelGGL(ctxB_kernel, dim3(BB), dim3(512), 0, stream,
                       part, ctx);
}

// Round 19
// 62.627 us; speedup vs baseline: 1.2971x; 1.0172x over previous
//
#include <hip/hip_runtime.h>
#include <math.h>

#define BB 64
#define SS 2048
#define DD 512
#define NU 512
#define WIN 128
#define NSLICE 4
#define G_OFF   0
#define ST_OFF  64
#define EN_OFF  128
#define M_OFF   256                  // [64][32] block-local max
#define S_OFF   (256 + BB * 32)      // [64][32] block-local exp-sum
#define PART_OFF 8192                // float offset of partials inside d_ws

__device__ __forceinline__ float wave_reduce_sum(float v) {
    #pragma unroll
    for (int off = 32; off > 0; off >>= 1)
        v += __shfl_down(v, off, 64);
    return v;
}

__device__ __forceinline__ float wave_reduce_max(float v) {
    #pragma unroll
    for (int off = 32; off > 0; off >>= 1)
        v = fmaxf(v, __shfl_down(v, off, 64));
    return v;
}

__device__ __forceinline__ float dot4(const float4 a, const float4 b) {
    return a.x * b.x + a.y * b.y + a.z * b.z + a.w * b.w;
}

// Kernel 1.
// Blocks [0, 64): p-path (16-lane-group GEMV over Wq).
// Blocks [64, 64+2048): score, 64 rows/block, 4 passes, 2-deep pipeline;
//   afterwards each block computes its local softmax stats (m_i, sum_i) over
//   its 64 scores and writes one pair -> ctxA no longer re-reads score rows.
__global__ __launch_bounds__(256, 4) void score_p_kernel(const float* __restrict__ query,
                                                         const float* __restrict__ keys,
                                                         const int* __restrict__ key_lengths,
                                                         const float* __restrict__ Wq,
                                                         const float* __restrict__ wp,
                                                         float* __restrict__ score,
                                                         float* __restrict__ ws) {
    const int t    = threadIdx.x;
    const int wave = t >> 6;
    const int lane = t & 63;
    const int g    = lane >> 4;   // 4 rows per wave pass
    const int w    = lane & 15;   // 16 lanes span one 512-float row

    if (blockIdx.x < BB) {
        // ---- p path: one block per batch ----
        const int b = blockIdx.x;
        __shared__ float act[NU];
        __shared__ float wsum[4];

        const float4* qv = (const float4*)(query + b * DD);
        const float4 q0 = qv[w],       q1 = qv[16 + w],  q2 = qv[32 + w],  q3 = qv[48 + w];
        const float4 q4 = qv[64 + w],  q5 = qv[80 + w],  q6 = qv[96 + w],  q7 = qv[112 + w];

        #pragma unroll 2
        for (int pass = 0; pass < 32; ++pass) {
            const int u = pass * 16 + wave * 4 + g;
            const float4* rv = (const float4*)(Wq + (size_t)u * DD);
            const float4 k0 = rv[w],       k1 = rv[16 + w],  k2 = rv[32 + w],  k3 = rv[48 + w];
            const float4 k4 = rv[64 + w],  k5 = rv[80 + w],  k6 = rv[96 + w],  k7 = rv[112 + w];
            const float s0 = dot4(k0, q0), s1 = dot4(k1, q1), s2 = dot4(k2, q2), s3 = dot4(k3, q3);
            const float s4 = dot4(k4, q4), s5 = dot4(k5, q5), s6 = dot4(k6, q6), s7 = dot4(k7, q7);
            float acc = ((s0 + s1) + (s2 + s3)) + ((s4 + s5) + (s6 + s7));
            #pragma unroll
            for (int m = 1; m < 16; m <<= 1)
                acc += __shfl_xor(acc, m, 64);
            if (w == 0) act[u] = tanhf(acc);
        }
        __syncthreads();

        float sv = act[t] * wp[t] + act[t + 256] * wp[t + 256];
        sv = wave_reduce_sum(sv);
        if (lane == 0) wsum[wave] = sv;
        __syncthreads();

        if (t == 0) {
            const float s = wsum[0] + wsum[1] + wsum[2] + wsum[3];
            const float sig = 1.0f / (1.0f + expf(-s));
            const float L = (float)key_lengths[b];
            const float p = L * sig;
            const int start = (int)(p - (float)WIN);   // trunc toward zero
            const int end   = (int)(p + (float)WIN);
            const float diff = L - p;
            const float gg = expf(-(diff * diff) / (float)WIN);
            ws[G_OFF + b] = gg;
            ((int*)ws)[ST_OFF + b] = start;
            ((int*)ws)[EN_OFF + b] = end;
        }
    } else {
        // ---- score path: software-pipelined 16-lane-group GEMV ----
        const int bid   = blockIdx.x - BB;
        const int b     = bid >> 5;   // 32 blocks per batch
        const int chunk = bid & 31;   // 64 rows per block
        const int r0    = chunk * 64 + wave * 16;
        __shared__ float sc_l[64];

        const float4* qv = (const float4*)(query + b * DD);
        const float4 q0 = qv[w],       q1 = qv[16 + w],  q2 = qv[32 + w],  q3 = qv[48 + w];
        const float4 q4 = qv[64 + w],  q5 = qv[80 + w],  q6 = qv[96 + w],  q7 = qv[112 + w];

        const float4* kb = (const float4*)(keys + (size_t)b * SS * DD);

        // prologue: load pass 0
        const float4* rv = kb + (size_t)(r0 + g) * (DD / 4);
        float4 k0 = rv[w],       k1 = rv[16 + w],  k2 = rv[32 + w],  k3 = rv[48 + w];
        float4 k4 = rv[64 + w],  k5 = rv[80 + w],  k6 = rv[96 + w],  k7 = rv[112 + w];

        #pragma unroll
        for (int p = 0; p < 4; ++p) {
            float4 n0, n1, n2, n3, n4, n5, n6, n7;
            if (p < 3) {   // issue next pass's loads before this pass's reduce
                const float4* nv = kb + (size_t)(r0 + (p + 1) * 4 + g) * (DD / 4);
                n0 = nv[w];       n1 = nv[16 + w];  n2 = nv[32 + w];  n3 = nv[48 + w];
                n4 = nv[64 + w];  n5 = nv[80 + w];  n6 = nv[96 + w];  n7 = nv[112 + w];
            }
            const float s0 = dot4(k0, q0), s1 = dot4(k1, q1), s2 = dot4(k2, q2), s3 = dot4(k3, q3);
            const float s4 = dot4(k4, q4), s5 = dot4(k5, q5), s6 = dot4(k6, q6), s7 = dot4(k7, q7);
            float acc = ((s0 + s1) + (s2 + s3)) + ((s4 + s5) + (s6 + s7));
            #pragma unroll
            for (int m = 1; m < 16; m <<= 1)
                acc += __shfl_xor(acc, m, 64);
            if (w == 0) {
                score[b * SS + r0 + p * 4 + g] = acc;
                sc_l[wave * 16 + p * 4 + g] = acc;
            }
            if (p < 3) {
                k0 = n0; k1 = n1; k2 = n2; k3 = n3;
                k4 = n4; k5 = n5; k6 = n6; k7 = n7;
            }
        }
        __syncthreads();

        // block-local softmax stats over the 64 scores (wave 0 only)
        if (t < 64) {
            const float v = sc_l[t];
            float m = wave_reduce_max(v);
            const float mloc = __shfl(m, 0, 64);
            const float ssum = wave_reduce_sum(expf(v - mloc));
            if (t == 0) {
                ws[M_OFF + b * 32 + chunk] = mloc;
                ws[S_OFF + b * 32 + chunk] = ssum;
            }
        }
    }
}

// Kernel 2 (stage A): merge 32 block-local stats (exact), then windowed
// weighted key sum over a contiguous slice. 512 threads, 4 rows in flight.
__global__ __launch_bounds__(512) void ctxA_kernel(const float* __restrict__ keys,
                                                   const float* __restrict__ score,
                                                   const float* __restrict__ ws,
                                                   float* __restrict__ part) {
    const int b     = blockIdx.x;
    const int slice = blockIdx.y;
    const int t     = threadIdx.x;
    const int wave  = t >> 6;
    const int lane  = t & 63;

    __shared__ float w_lds[72];
    __shared__ float stat_l[2];
    __shared__ float4 part_l[3][128];

    // merge per-chunk (m_i, s_i): mx = max m_i; tot = sum s_i * exp(m_i - mx)
    if (wave == 0) {
        const float mi = (lane < 32) ? ws[M_OFF + b * 32 + lane] : -INFINITY;
        float m = wave_reduce_max(mi);
        const float mx0 = __shfl(m, 0, 64);
        const float si = (lane < 32) ? ws[S_OFF + b * 32 + lane] * expf(mi - mx0) : 0.f;
        float s = wave_reduce_sum(si);
        if (lane == 0) { stat_l[0] = mx0; stat_l[1] = 1.0f / s; }
    }
    __syncthreads();
    const float mx  = stat_l[0];
    const float inv = stat_l[1];

    const float gg   = ws[G_OFF + b];
    const int start  = ((const int*)ws)[ST_OFF + b];
    const int end    = ((const int*)ws)[EN_OFF + b];
    const int s_lo   = max(start, 0);
    const int s_hi   = min(end, SS);
    const int width  = s_hi - s_lo;              // in [0, 257]
    const int sliceN = (width + NSLICE - 1) / NSLICE;
    const int i_lo   = slice * sliceN;
    const int i_hi   = min(i_lo + sliceN, width);
    const int n      = i_hi - i_lo;              // may be <= 0

    const float* srow = score + b * SS;
    for (int i = t; i < n; i += 512)
        w_lds[i] = expf(srow[s_lo + i_lo + i] - mx) * inv * gg;
    __syncthreads();

    // linear stream: 4 rows x 128 float4-cols per step, thread owns col group c4
    const int myrow = t >> 7;        // 0..3
    const int c4    = t & 127;
    const float4* kb = (const float4*)(keys + ((size_t)b * SS + s_lo + i_lo) * DD);

    float4 acc = make_float4(0.f, 0.f, 0.f, 0.f);
    for (int i = myrow; i < n; i += 4) {
        const float4 k = kb[(size_t)i * (DD / 4) + c4];
        const float wg = w_lds[i];
        acc.x += wg * k.x; acc.y += wg * k.y; acc.z += wg * k.z; acc.w += wg * k.w;
    }

    if (myrow) part_l[myrow - 1][c4] = acc;
    __syncthreads();
    if (myrow == 0) {
        #pragma unroll
        for (int r = 0; r < 3; ++r) {
            const float4 o = part_l[r][c4];
            acc.x += o.x; acc.y += o.y; acc.z += o.z; acc.w += o.w;
        }
        ((float4*)part)[((size_t)b * NSLICE + slice) * 128 + c4] = acc;
    }
}

// Kernel 2 (stage B): ctx[b][d] = sum over slices of partials
__global__ __launch_bounds__(512) void ctxB_kernel(const float* __restrict__ part,
                                                   float* __restrict__ ctx) {
    const int b = blockIdx.x;
    const int d = threadIdx.x;
    float s = 0.f;
    #pragma unroll
    for (int sl = 0; sl < NSLICE; ++sl)
        s += part[((size_t)b * NSLICE + sl) * DD + d];
    ctx[b * DD + d] = s;
}

extern "C" void kernel_launch(void* const* d_in, const int* in_sizes, int n_in,
                              void* d_out, int out_size, void* d_ws, size_t ws_size,
                              hipStream_t stream) {
    const float* query       = (const float*)d_in[0];
    const float* keys        = (const float*)d_in[1];
    const int*   key_lengths = (const int*)d_in[2];
    const float* Wq          = (const float*)d_in[3];
    const float* wp          = (const float*)d_in[4];

    float* ctx   = (float*)d_out;             // [64, 512]
    float* score = (float*)d_out + BB * DD;   // [64, 2048]
    float* ws    = (float*)d_ws;              // {g, start, end, m[64][32], s[64][32]}
    float* part  = (float*)d_ws + PART_OFF;   // [64, NSLICE, 512]

    hipLaunchKernelGGL(score_p_kernel, dim3(BB + BB * 32), dim3(256), 0, stream,
                       query, keys, key_lengths, Wq, wp, score, ws);
    hipLaunchKernelGGL(ctxA_kernel, dim3(BB, NSLICE), dim3(512), 0, stream,
                       keys, score, ws, part);
    hipLaunchKernelGGL(ctxB_kernel, dim3(BB), dim3(512), 0, stream,
                       part, ctx);
}